// Round 9
// baseline (1091.318 us; speedup 1.0000x reference)
//
#include <hip/hip_runtime.h>
#include <cstdint>
#include <cstddef>

#define B_ROWS 32768
#define ZD 64
#define XD 256
#define HID 512
#define T_STEPS 8
#define MULT 23
#define MPAD 24
#define NOUT 1472
#define NPAD 1536      // 64 * MPAD
#define K1 320         // ZD + XD
#define PSTRIDE 200    // padded row stride (ushorts) for p-tile in LDS

typedef float f32x4 __attribute__((ext_vector_type(4)));
typedef short s16x8 __attribute__((ext_vector_type(8)));

__device__ __forceinline__ unsigned short f2bf(float f) {
  unsigned int u = __float_as_uint(f);
  u = (u + 0x7FFFu + ((u >> 16) & 1u)) >> 16;   // RNE, no NaN inputs here
  return (unsigned short)u;
}
__device__ __forceinline__ float bf2f(unsigned short s) {
  return __uint_as_float(((unsigned int)s) << 16);
}

// Degree-sort permutation of the hidden dim. deg(i) = (i%63)+1; count(g) = 9 (g<=8) else 8.
__device__ __forceinline__ int permP(int n) {
  return (n < 72) ? (n / 9) + 63 * (n % 9)
                  : ((n - 72) >> 3) + 8 + 63 * ((n - 72) & 7);
}
__device__ __forceinline__ int degP(int n) {
  return (n < 72) ? (n / 9) + 1 : ((n - 72) >> 3) + 9;
}

// ---------------- merged prep kernels ----------------

__global__ void prep_weights(const float* __restrict__ W1, const float* __restrict__ Wc,
                             const float* __restrict__ W2, const float* __restrict__ W3,
                             const float* __restrict__ b1, const float* __restrict__ bc,
                             const float* __restrict__ b2, const float* __restrict__ b3,
                             unsigned short* __restrict__ w1c, unsigned short* __restrict__ w2c,
                             unsigned short* __restrict__ w3c,
                             float* __restrict__ ob1, float* __restrict__ ob2,
                             float* __restrict__ ob3) {
  const int S1 = T_STEPS * HID * K1;
  const int S2 = S1 + T_STEPS * HID * HID;
  const int S3 = S2 + T_STEPS * NPAD * HID;
  const int S4 = S3 + T_STEPS * HID;
  const int S5 = S4 + T_STEPS * HID;
  const int S6 = S5 + T_STEPS * NPAD;
  int i = blockIdx.x * 256 + threadIdx.x;
  if (i < S1) {
    int t = i / (HID * K1);
    int r = i - t * (HID * K1);
    int n = r / K1;          // permuted hidden row
    int k = r - n * K1;
    int on = permP(n);
    float v;
    if (k < ZD) v = ((on % 63) >= k) ? W1[((size_t)t * HID + on) * ZD + k] : 0.0f;
    else        v = Wc[((size_t)t * HID + on) * XD + (k - ZD)];
    w1c[i] = f2bf(v);
  } else if (i < S2) {
    int j = i - S1;
    int t = j / (HID * HID);
    int r = j - t * (HID * HID);
    int n = r / HID;
    int k = r - n * HID;
    float v = 0.0f;
    if (degP(n) >= degP(k))
      v = W2[((size_t)t * HID + permP(n)) * HID + permP(k)];
    w2c[j] = f2bf(v);
  } else if (i < S3) {
    int j = i - S2;
    int t = j / (NPAD * HID);
    int r = j - t * (NPAD * HID);
    int n = r / HID;
    int k = r - n * HID;
    int d = n / MPAD;
    int jj = n - d * MPAD;
    float v = 0.0f;
    if (jj < MULT && d >= degP(k))
      v = W3[((size_t)t * NOUT + d * MULT + jj) * HID + permP(k)];
    w3c[j] = f2bf(v);
  } else if (i < S4) {
    int j = i - S3;
    int t = j / HID, n = j - t * HID;
    int on = permP(n);
    ob1[j] = b1[(size_t)t * HID + on] + bc[(size_t)t * HID + on];
  } else if (i < S5) {
    int j = i - S4;
    int t = j / HID, n = j - t * HID;
    ob2[j] = b2[(size_t)t * HID + permP(n)];
  } else if (i < S6) {
    int j = i - S5;
    int t = j / NPAD;
    int n = j - t * NPAD;
    int d = n / MPAD;
    int jj = n - d * MPAD;
    ob3[j] = (jj < MULT) ? b3[(size_t)t * NOUT + d * MULT + jj] : 0.0f;
  }
}

__global__ void prep_data(const float* __restrict__ x, const float* __restrict__ z,
                          unsigned short* __restrict__ A1,
                          float* __restrict__ curf, float* __restrict__ lad) {
  const int SX = B_ROWS * XD;
  int i = blockIdx.x * 256 + threadIdx.x;
  if (i < SX) {
    int b = i >> 8;
    int j = i & 255;
    A1[(size_t)b * K1 + ZD + j] = f2bf(x[i]);
  } else {
    int j = i - SX;
    if (j < B_ROWS * ZD) {
      int b = j >> 6;
      int d = j & 63;
      float zv = z[j];
      A1[(size_t)b * K1 + d] = f2bf(zv);
      curf[j] = zv;
      if (d == 0) lad[b] = 0.0f;
    }
  }
}

// ---------------- shared GEMM machinery ----------------

#define ASYNC16(gp, lp) __builtin_amdgcn_global_load_lds( \
    (__attribute__((address_space(1))) unsigned int*)(gp), \
    (__attribute__((address_space(3))) unsigned int*)(lp), 16, 0, 0)

// ---------------- GEMM1/2: C[M,512] = A[M,K]@W[512,K]^T + bias, opt relu ----------
// OPERAND-SWAPPED: weights are the MFMA A-operand -> lane holds 4 consecutive
// param-cols of one batch row -> b64 C-stores. grid MUST be (4, 256).
// BK=64 (two 32-k chunks per barrier pair). tri=1: K_eff = min(K, 192+n0).

__global__ __launch_bounds__(256, 2) void gemm_bias(
    const unsigned short* __restrict__ A,     // activations [M][K]
    const unsigned short* __restrict__ Bw,    // weights [N][K]
    const float* __restrict__ bias,
    unsigned short* __restrict__ C,
    int M, int N, int K, int relu, int tri)
{
  __shared__ alignas(16) unsigned short lA[2 * 128 * 32];   // activation rows
  __shared__ alignas(16) unsigned short lB[2 * 128 * 32];   // weight rows

  const int tid  = threadIdx.x;
  const int lane = tid & 63;
  const int wave = tid >> 6;

  const int lin = blockIdx.y * 4 + blockIdx.x;
  const int xcd = lin & 7;
  const int loc = lin >> 3;
  const int m0 = (xcd * 32 + (loc >> 2)) * 128;   // batch base
  const int n0 = (loc & 3) * 128;                 // param base
  const int Keff = tri ? min(K, 192 + n0) : K;

  const int wp = (wave >> 1) * 64;   // param strip
  const int wb = (wave & 1) * 64;    // batch strip
  const int fr = lane & 15;
  const int quad = lane >> 4;
  const int fk = quad * 8;           // k offset (shorts) within a 32-k row

  // bias as per-lane float4 (params wp+pi*16+quad*4 .. +3)
  float4 bv[4];
#pragma unroll
  for (int pi = 0; pi < 4; pi++)
    bv[pi] = *(const float4*)(bias + n0 + wp + pi * 16 + quad * 4);

  const int f    = tid * 16;
  const int row0 = f >> 6;       // 64B per 32-elem row
  const int colb = f & 63;

  char* gA0 = (char*)A  + ((size_t)(m0 + row0) * K) * 2 + colb;
  char* gA1 = gA0 + (size_t)64 * K * 2;
  char* gB0 = (char*)Bw + ((size_t)(n0 + row0) * K) * 2 + colb;
  char* gB1 = gB0 + (size_t)64 * K * 2;

  unsigned short* lA0 = lA + wave * 512;
  unsigned short* lA1 = lA + 2048 + wave * 512;
  unsigned short* lB0 = lB + wave * 512;
  unsigned short* lB1 = lB + 2048 + wave * 512;

  f32x4 acc[4][4];   // [param][batch]
#pragma unroll
  for (int i = 0; i < 4; i++)
#pragma unroll
    for (int j = 0; j < 4; j++) acc[i][j] = (f32x4){0.f, 0.f, 0.f, 0.f};

  for (int k0 = 0; k0 < Keff; k0 += 64) {
    ASYNC16(gA0, lA0);
    ASYNC16(gA1, lA1);
    ASYNC16(gB0, lB0);
    ASYNC16(gB1, lB1);
    ASYNC16(gA0 + 64, lA0 + 4096);
    ASYNC16(gA1 + 64, lA1 + 4096);
    ASYNC16(gB0 + 64, lB0 + 4096);
    ASYNC16(gB1 + 64, lB1 + 4096);
    gA0 += 128; gA1 += 128; gB0 += 128; gB1 += 128;
    __syncthreads();

    s16x8 aw0[4], aw1[4], bx0[4], bx1[4];
#pragma unroll
    for (int pi = 0; pi < 4; pi++) {
      aw0[pi] = *(const s16x8*)(lB + (wp + pi * 16 + fr) * 32 + fk);
      aw1[pi] = *(const s16x8*)(lB + 4096 + (wp + pi * 16 + fr) * 32 + fk);
    }
#pragma unroll
    for (int bj = 0; bj < 4; bj++) {
      bx0[bj] = *(const s16x8*)(lA + (wb + bj * 16 + fr) * 32 + fk);
      bx1[bj] = *(const s16x8*)(lA + 4096 + (wb + bj * 16 + fr) * 32 + fk);
    }

#pragma unroll
    for (int pi = 0; pi < 4; pi++)
#pragma unroll
      for (int bj = 0; bj < 4; bj++)
        acc[pi][bj] = __builtin_amdgcn_mfma_f32_16x16x32_bf16(aw0[pi], bx0[bj], acc[pi][bj], 0, 0, 0);
#pragma unroll
    for (int pi = 0; pi < 4; pi++)
#pragma unroll
      for (int bj = 0; bj < 4; bj++)
        acc[pi][bj] = __builtin_amdgcn_mfma_f32_16x16x32_bf16(aw1[pi], bx1[bj], acc[pi][bj], 0, 0, 0);
    __syncthreads();
  }

  // epilogue: lane holds params (wp+pi*16+quad*4 .. +3) of batch row (wb+bj*16+fr)
#pragma unroll
  for (int bj = 0; bj < 4; bj++) {
    const size_t row = m0 + wb + bj * 16 + fr;
#pragma unroll
    for (int pi = 0; pi < 4; pi++) {
      union { unsigned long long u; unsigned short s[4]; } pk;
#pragma unroll
      for (int r = 0; r < 4; r++) {
        float v = acc[pi][bj][r] + bv[pi][r];
        if (relu) v = fmaxf(v, 0.0f);
        pk.s[r] = f2bf(v);
      }
      *(unsigned long long*)(C + row * N + n0 + wp + pi * 16 + quad * 4) = pk.u;
    }
  }
}

// ---------------- spline math (per (b,d)) ----------------

__device__ __forceinline__ void rq_spline(const unsigned short* __restrict__ pp,
                                          float zv, float& zn, float& lad) {
  const float TAILC = 25.0f;
  const float MIN_WC = 0.001f;
  const float MIN_DC = 0.001f;
  const float SCALE = 0.044194173824159216f; // 1/sqrt(512)

  s16x8 vw = *(const s16x8*)(pp);
  s16x8 vh = *(const s16x8*)(pp + 8);
  s16x8 vd = *(const s16x8*)(pp + 16);

  bool inside = (zv >= -TAILC) && (zv <= TAILC);
  float z_in = fminf(fmaxf(zv, -TAILC), TAILC);

  float ew[8], eh[8], sw = 0.f, sh = 0.f;
#pragma unroll
  for (int i = 0; i < 8; i++) {
    float u = fminf(fmaxf(bf2f((unsigned short)vw[i]) * SCALE, -30.f), 30.f);
    ew[i] = __expf(u); sw += ew[i];
  }
#pragma unroll
  for (int i = 0; i < 8; i++) {
    float u = fminf(fmaxf(bf2f((unsigned short)vh[i]) * SCALE, -30.f), 30.f);
    eh[i] = __expf(u); sh += eh[i];
  }
  float iw = (1.0f - 8.0f * MIN_WC) / sw;
  float ih = (1.0f - 8.0f * MIN_WC) / sh;

  float cumw[9], cumh[9];
  cumw[0] = -TAILC; cumh[0] = -TAILC;
  float cw = 0.f, ch = 0.f;
#pragma unroll
  for (int i = 0; i < 8; i++) {
    cw += MIN_WC + ew[i] * iw;
    ch += MIN_WC + eh[i] * ih;
    cumw[i + 1] = fmaf(2.0f * TAILC, cw, -TAILC);
    cumh[i + 1] = fmaf(2.0f * TAILC, ch, -TAILC);
  }
  cumw[8] = TAILC; cumh[8] = TAILC;

  int idx = 0;
#pragma unroll
  for (int i = 1; i < 8; i++) idx += (z_in >= cumw[i]) ? 1 : 0;

  float in_cw = 0.f, cw1 = 1.f, in_ch = 0.f, ch1 = 1.f, u0 = 0.f, u1 = 0.f;
#pragma unroll
  for (int i = 0; i < 8; i++) {
    if (i == idx) {
      in_cw = cumw[i]; cw1 = cumw[i + 1];
      in_ch = cumh[i]; ch1 = cumh[i + 1];
      u0 = (i > 0) ? bf2f((unsigned short)vd[i - 1]) : 0.0f;
      u1 = (i < 7) ? bf2f((unsigned short)vd[i]) : 0.0f;
    }
  }
  float dd0 = (idx == 0) ? 1.0f
            : MIN_DC + fmaxf(u0, 0.f) + __logf(1.0f + __expf(-fabsf(u0)));
  float dd1 = (idx == 7) ? 1.0f
            : MIN_DC + fmaxf(u1, 0.f) + __logf(1.0f + __expf(-fabsf(u1)));
  float in_w = cw1 - in_cw;
  float in_h = ch1 - in_ch;

  float delta = in_h / in_w;
  float th  = (z_in - in_cw) / in_w;
  float th1 = th * (1.0f - th);
  float th2 = th * th;
  float num = in_h * (delta * th2 + dd0 * th1);
  float den = delta + (dd0 + dd1 - 2.0f * delta) * th1;
  float outz = in_ch + num / den;
  float omt = 1.0f - th;
  float dnum = delta * delta * (dd1 * th2 + 2.0f * delta * th1 + dd0 * omt * omt);
  float l = __logf(dnum) - 2.0f * __logf(den);

  zn  = inside ? outz : zv;
  lad = inside ? l : 0.0f;
}

// ---------------- fused GEMM3 + spline, 128x192 tile, triangular K, BK=64 ---------
// OPERAND-SWAPPED: pT writes are b64 (lane holds 4 consecutive param-cols of one
// batch row). grid MUST be (8, 256). K_eff = 64*(bn+1).

__global__ __launch_bounds__(256, 2) void gemm3_spline(
    const unsigned short* __restrict__ A,     // h2 [B][512] (k degree-permuted)
    const unsigned short* __restrict__ Bw,    // w3c[t] [1536][512] (MPAD rows, perm k)
    const float* __restrict__ bias,           // [1536] (MPAD layout)
    float* __restrict__ curf,                 // [B][64]
    unsigned short* __restrict__ A1,          // [B][320]
    float* __restrict__ lad_acc)              // [B]
{
  __shared__ alignas(16) union {
    struct { unsigned short A[2 * 128 * 32]; unsigned short B[2 * 192 * 32]; } g;
    unsigned short p[128 * PSTRIDE];
  } sm;

  const int tid  = threadIdx.x;
  const int lane = tid & 63;
  const int wave = tid >> 6;

  const int lin = blockIdx.y * 8 + blockIdx.x;
  const int xcd = lin & 7;
  const int loc = lin >> 3;
  const int m0 = (xcd * 32 + (loc >> 3)) * 128;
  const int bn = loc & 7;
  const int n0 = bn * 192;
  const int Keff = 64 * (bn + 1);   // dims 8bn..8bn+7 need h_deg <= 8bn+7

  const int wp = (wave >> 1) * 96;   // param strip
  const int wb = (wave & 1) * 64;    // batch strip
  const int fr = lane & 15;
  const int quad = lane >> 4;
  const int fk = quad * 8;

  // spline-phase mapping (R7/R8, conflict-light)
  const int srow = tid & 127;
  const int sb = m0 + srow;
  const int dl0 = (tid >> 7) * 4;
  const int d0 = bn * 8 + dl0;
  float4 cz = *(const float4*)(curf + (size_t)sb * ZD + d0);
  float4 bv[6];
#pragma unroll
  for (int pi = 0; pi < 6; pi++)
    bv[pi] = *(const float4*)(bias + n0 + wp + pi * 16 + quad * 4);

  const int f    = tid * 16;
  const int row0 = f >> 6;
  const int colb = f & 63;
  const int K = HID;

  char* gA0 = (char*)A  + ((size_t)(m0 + row0) * K) * 2 + colb;
  char* gA1 = gA0 + (size_t)64 * K * 2;
  char* gB0 = (char*)Bw + ((size_t)(n0 + row0) * K) * 2 + colb;
  char* gB1 = gB0 + (size_t)64 * K * 2;
  char* gB2 = gB1 + (size_t)64 * K * 2;

  unsigned short* lA0 = sm.g.A + wave * 512;
  unsigned short* lA1 = sm.g.A + 2048 + wave * 512;
  unsigned short* lB0 = sm.g.B + wave * 512;
  unsigned short* lB1 = sm.g.B + 2048 + wave * 512;
  unsigned short* lB2 = sm.g.B + 4096 + wave * 512;

  f32x4 acc[6][4];   // [param][batch]
#pragma unroll
  for (int i = 0; i < 6; i++)
#pragma unroll
    for (int j = 0; j < 4; j++) acc[i][j] = (f32x4){0.f, 0.f, 0.f, 0.f};

  for (int k0 = 0; k0 < Keff; k0 += 64) {
    ASYNC16(gA0, lA0);
    ASYNC16(gA1, lA1);
    ASYNC16(gB0, lB0);
    ASYNC16(gB1, lB1);
    ASYNC16(gB2, lB2);
    ASYNC16(gA0 + 64, lA0 + 4096);
    ASYNC16(gA1 + 64, lA1 + 4096);
    ASYNC16(gB0 + 64, lB0 + 6144);
    ASYNC16(gB1 + 64, lB1 + 6144);
    ASYNC16(gB2 + 64, lB2 + 6144);
    gA0 += 128; gA1 += 128; gB0 += 128; gB1 += 128; gB2 += 128;
    __syncthreads();

    s16x8 aw0[6], aw1[6], bx0[4], bx1[4];
#pragma unroll
    for (int pi = 0; pi < 6; pi++) {
      aw0[pi] = *(const s16x8*)(sm.g.B + (wp + pi * 16 + fr) * 32 + fk);
      aw1[pi] = *(const s16x8*)(sm.g.B + 6144 + (wp + pi * 16 + fr) * 32 + fk);
    }
#pragma unroll
    for (int bj = 0; bj < 4; bj++) {
      bx0[bj] = *(const s16x8*)(sm.g.A + (wb + bj * 16 + fr) * 32 + fk);
      bx1[bj] = *(const s16x8*)(sm.g.A + 4096 + (wb + bj * 16 + fr) * 32 + fk);
    }

#pragma unroll
    for (int pi = 0; pi < 6; pi++)
#pragma unroll
      for (int bj = 0; bj < 4; bj++)
        acc[pi][bj] = __builtin_amdgcn_mfma_f32_16x16x32_bf16(aw0[pi], bx0[bj], acc[pi][bj], 0, 0, 0);
#pragma unroll
    for (int pi = 0; pi < 6; pi++)
#pragma unroll
      for (int bj = 0; bj < 4; bj++)
        acc[pi][bj] = __builtin_amdgcn_mfma_f32_16x16x32_bf16(aw1[pi], bx1[bj], acc[pi][bj], 0, 0, 0);
    __syncthreads();
  }

  // accumulator + bias -> pT: b64 writes (4 consecutive param-cols per lane)
#pragma unroll
  for (int bj = 0; bj < 4; bj++) {
    const int brow = wb + bj * 16 + fr;
#pragma unroll
    for (int pi = 0; pi < 6; pi++) {
      union { unsigned long long u; unsigned short s[4]; } pk;
#pragma unroll
      for (int r = 0; r < 4; r++)
        pk.s[r] = f2bf(acc[pi][bj][r] + bv[pi][r]);
      *(unsigned long long*)(sm.p + brow * PSTRIDE + wp + pi * 16 + quad * 4) = pk.u;
    }
  }
  __syncthreads();

  // spline: 2 threads per row, 4 dims each
  const unsigned short* pp = sm.p + srow * PSTRIDE + dl0 * MPAD;
  float zn0, zn1, zn2, zn3, l0, l1, l2, l3;
  rq_spline(pp,            cz.x, zn0, l0);
  rq_spline(pp + MPAD,     cz.y, zn1, l1);
  rq_spline(pp + 2 * MPAD, cz.z, zn2, l2);
  rq_spline(pp + 3 * MPAD, cz.w, zn3, l3);

  *(float4*)(curf + (size_t)sb * ZD + d0) = make_float4(zn0, zn1, zn2, zn3);
  union { unsigned int u[2]; unsigned short s[4]; } pk;
  pk.s[0] = f2bf(zn0); pk.s[1] = f2bf(zn1); pk.s[2] = f2bf(zn2); pk.s[3] = f2bf(zn3);
  *(uint2*)(A1 + (size_t)sb * K1 + d0) = make_uint2(pk.u[0], pk.u[1]);

  atomicAdd(&lad_acc[sb], l0 + l1 + l2 + l3);
}

// ---------------- finalize ----------------

__global__ void finalize(const float* __restrict__ curf, const float* __restrict__ lad,
                         float* __restrict__ out) {
  int i = blockIdx.x * 256 + threadIdx.x;
  int b = i >> 6;
  int d = i & 63;
  float c = curf[i];
  float q = c * c;
#pragma unroll
  for (int off = 32; off > 0; off >>= 1) q += __shfl_xor(q, off, 64);
  if (d == 0) out[b] = lad[b] - 0.5f * q - 58.81206612509905f;
}

// ---------------- launch ----------------

extern "C" void kernel_launch(void* const* d_in, const int* in_sizes, int n_in,
                              void* d_out, int out_size, void* d_ws, size_t ws_size,
                              hipStream_t stream)
{
  const float* z  = (const float*)d_in[0];
  const float* x  = (const float*)d_in[1];
  const float* W1 = (const float*)d_in[2];
  const float* b1 = (const float*)d_in[3];
  const float* Wc = (const float*)d_in[4];
  const float* bc = (const float*)d_in[5];
  const float* W2 = (const float*)d_in[6];
  const float* b2 = (const float*)d_in[7];
  const float* W3 = (const float*)d_in[8];
  const float* b3 = (const float*)d_in[9];
  float* out = (float*)d_out;
  char* ws = (char*)d_ws;

  size_t oA1 = 0;
  size_t oH1 = oA1 + (size_t)B_ROWS * K1 * 2;
  size_t oH2 = oH1 + (size_t)B_ROWS * HID * 2;
  size_t oCU = oH2 + (size_t)B_ROWS * HID * 2;
  size_t oLA = oCU + (size_t)B_ROWS * ZD * 4;
  size_t oW1 = oLA + (size_t)B_ROWS * 4;
  size_t oW2 = oW1 + (size_t)T_STEPS * HID * K1 * 2;
  size_t oW3 = oW2 + (size_t)T_STEPS * HID * HID * 2;
  size_t oB1 = oW3 + (size_t)T_STEPS * NPAD * HID * 2;
  size_t oB2 = oB1 + (size_t)T_STEPS * HID * 4;
  size_t oB3 = oB2 + (size_t)T_STEPS * HID * 4;

  unsigned short* A1  = (unsigned short*)(ws + oA1);
  unsigned short* h1  = (unsigned short*)(ws + oH1);
  unsigned short* h2  = (unsigned short*)(ws + oH2);
  float* curf = (float*)(ws + oCU);
  float* lad  = (float*)(ws + oLA);
  unsigned short* w1c = (unsigned short*)(ws + oW1);
  unsigned short* w2c = (unsigned short*)(ws + oW2);
  unsigned short* w3c = (unsigned short*)(ws + oW3);
  float* b1c = (float*)(ws + oB1);
  float* b2p = (float*)(ws + oB2);
  float* b3c = (float*)(ws + oB3);

  const int prepw_total = T_STEPS * (HID * K1 + HID * HID + NPAD * HID + 2 * HID + NPAD);
  prep_weights<<<(prepw_total + 255) / 256, 256, 0, stream>>>(
      W1, Wc, W2, W3, b1, bc, b2, b3, w1c, w2c, w3c, b1c, b2p, b3c);
  const int prepd_total = B_ROWS * (XD + ZD);
  prep_data<<<(prepd_total + 255) / 256, 256, 0, stream>>>(x, z, A1, curf, lad);

  for (int t = 0; t < T_STEPS; ++t) {
    gemm_bias<<<dim3(4, B_ROWS / 128), 256, 0, stream>>>(
        A1, w1c + (size_t)t * HID * K1, b1c + (size_t)t * HID, h1,
        B_ROWS, HID, K1, 0, 0);
    gemm_bias<<<dim3(4, B_ROWS / 128), 256, 0, stream>>>(
        h1, w2c + (size_t)t * HID * HID, b2p + (size_t)t * HID, h2,
        B_ROWS, HID, HID, 1, 1);
    gemm3_spline<<<dim3(8, B_ROWS / 128), 256, 0, stream>>>(
        h2, w3c + (size_t)t * NPAD * HID, b3c + (size_t)t * NPAD,
        curf, A1, lad);
  }
  finalize<<<B_ROWS * ZD / 256, 256, 0, stream>>>(curf, lad, out);
}

// Round 10
// 963.251 us; speedup vs baseline: 1.1330x; 1.1330x over previous
//
#include <hip/hip_runtime.h>
#include <cstdint>
#include <cstddef>

#define B_ROWS 32768
#define ZD 64
#define XD 256
#define HID 512
#define T_STEPS 8
#define MULT 23
#define MPAD 24
#define NOUT 1472
#define NPAD 1536      // 64 * MPAD
#define K1 320         // ZD + XD
#define PSTRIDE 200    // padded row stride (ushorts) for p-tile in LDS

typedef float f32x4 __attribute__((ext_vector_type(4)));
typedef short s16x8 __attribute__((ext_vector_type(8)));

__device__ __forceinline__ unsigned short f2bf(float f) {
  unsigned int u = __float_as_uint(f);
  u = (u + 0x7FFFu + ((u >> 16) & 1u)) >> 16;   // RNE, no NaN inputs here
  return (unsigned short)u;
}
__device__ __forceinline__ float bf2f(unsigned short s) {
  return __uint_as_float(((unsigned int)s) << 16);
}

// Degree-sort permutation of the hidden dim. deg(i) = (i%63)+1; count(g) = 9 (g<=8) else 8.
__device__ __forceinline__ int permP(int n) {
  return (n < 72) ? (n / 9) + 63 * (n % 9)
                  : ((n - 72) >> 3) + 8 + 63 * ((n - 72) & 7);
}
__device__ __forceinline__ int degP(int n) {
  return (n < 72) ? (n / 9) + 1 : ((n - 72) >> 3) + 9;
}

// ---------------- merged prep kernels ----------------

__global__ void prep_weights(const float* __restrict__ W1, const float* __restrict__ Wc,
                             const float* __restrict__ W2, const float* __restrict__ W3,
                             const float* __restrict__ b1, const float* __restrict__ bc,
                             const float* __restrict__ b2, const float* __restrict__ b3,
                             unsigned short* __restrict__ w1c, unsigned short* __restrict__ w2c,
                             unsigned short* __restrict__ w3c,
                             float* __restrict__ ob1, float* __restrict__ ob2,
                             float* __restrict__ ob3) {
  const int S1 = T_STEPS * HID * K1;
  const int S2 = S1 + T_STEPS * HID * HID;
  const int S3 = S2 + T_STEPS * NPAD * HID;
  const int S4 = S3 + T_STEPS * HID;
  const int S5 = S4 + T_STEPS * HID;
  const int S6 = S5 + T_STEPS * NPAD;
  int i = blockIdx.x * 256 + threadIdx.x;
  if (i < S1) {
    int t = i / (HID * K1);
    int r = i - t * (HID * K1);
    int n = r / K1;          // permuted hidden row
    int k = r - n * K1;
    int on = permP(n);
    float v;
    if (k < ZD) v = ((on % 63) >= k) ? W1[((size_t)t * HID + on) * ZD + k] : 0.0f;
    else        v = Wc[((size_t)t * HID + on) * XD + (k - ZD)];
    w1c[i] = f2bf(v);
  } else if (i < S2) {
    int j = i - S1;
    int t = j / (HID * HID);
    int r = j - t * (HID * HID);
    int n = r / HID;
    int k = r - n * HID;
    float v = 0.0f;
    if (degP(n) >= degP(k))
      v = W2[((size_t)t * HID + permP(n)) * HID + permP(k)];
    w2c[j] = f2bf(v);
  } else if (i < S3) {
    int j = i - S2;
    int t = j / (NPAD * HID);
    int r = j - t * (NPAD * HID);
    int n = r / HID;
    int k = r - n * HID;
    int d = n / MPAD;
    int jj = n - d * MPAD;
    float v = 0.0f;
    if (jj < MULT && d >= degP(k))
      v = W3[((size_t)t * NOUT + d * MULT + jj) * HID + permP(k)];
    w3c[j] = f2bf(v);
  } else if (i < S4) {
    int j = i - S3;
    int t = j / HID, n = j - t * HID;
    int on = permP(n);
    ob1[j] = b1[(size_t)t * HID + on] + bc[(size_t)t * HID + on];
  } else if (i < S5) {
    int j = i - S4;
    int t = j / HID, n = j - t * HID;
    ob2[j] = b2[(size_t)t * HID + permP(n)];
  } else if (i < S6) {
    int j = i - S5;
    int t = j / NPAD;
    int n = j - t * NPAD;
    int d = n / MPAD;
    int jj = n - d * MPAD;
    ob3[j] = (jj < MULT) ? b3[(size_t)t * NOUT + d * MULT + jj] : 0.0f;
  }
}

__global__ void prep_data(const float* __restrict__ x, const float* __restrict__ z,
                          unsigned short* __restrict__ A1,
                          float* __restrict__ curf, float* __restrict__ out) {
  const int SX = B_ROWS * XD;
  int i = blockIdx.x * 256 + threadIdx.x;
  if (i < SX) {
    int b = i >> 8;
    int j = i & 255;
    A1[(size_t)b * K1 + ZD + j] = f2bf(x[i]);
  } else {
    int j = i - SX;
    if (j < B_ROWS * ZD) {
      int b = j >> 6;
      int d = j & 63;
      float zv = z[j];
      A1[(size_t)b * K1 + d] = f2bf(zv);
      curf[j] = zv;
      if (d == 0) out[b] = -58.81206612509905f;   // -0.5*64*ln(2pi); lad accumulates here
    }
  }
}

// ---------------- shared GEMM machinery ----------------

#define ASYNC16(gp, lp) __builtin_amdgcn_global_load_lds( \
    (__attribute__((address_space(1))) unsigned int*)(gp), \
    (__attribute__((address_space(3))) unsigned int*)(lp), 16, 0, 0)

// ---------------- GEMM1/2: C[M,512] = A[M,K]@W[512,K]^T + bias, opt relu ----------
// grid MUST be (4, 256). BK=64 staged as TWO 32-k chunks per barrier pair.
// tri=1: triangular K_eff = min(K, 192+n0). launch_bounds(256,3): cap 170 regs
// (need ~150: acc 64 + ~85 arch) -> 3 blocks/CU, LDS 32KB*3 = 96KB. No spill.

__global__ __launch_bounds__(256, 3) void gemm_bias(
    const unsigned short* __restrict__ A,
    const unsigned short* __restrict__ Bw,
    const float* __restrict__ bias,
    unsigned short* __restrict__ C,
    int M, int N, int K, int relu, int tri)
{
  __shared__ alignas(16) unsigned short lA[2 * 128 * 32];
  __shared__ alignas(16) unsigned short lB[2 * 128 * 32];

  const int tid  = threadIdx.x;
  const int lane = tid & 63;
  const int wave = tid >> 6;

  const int lin = blockIdx.y * 4 + blockIdx.x;
  const int xcd = lin & 7;
  const int loc = lin >> 3;
  const int m0 = (xcd * 32 + (loc >> 2)) * 128;
  const int n0 = (loc & 3) * 128;
  const int Keff = tri ? min(K, 192 + n0) : K;

  const int wm = (wave >> 1) * 64;
  const int wn = (wave & 1) * 64;

  const int f    = tid * 16;
  const int row0 = f >> 6;       // 64B per 32-elem row
  const int colb = f & 63;

  char* gA0 = (char*)A  + ((size_t)(m0 + row0) * K) * 2 + colb;
  char* gA1 = gA0 + (size_t)64 * K * 2;
  char* gB0 = (char*)Bw + ((size_t)(n0 + row0) * K) * 2 + colb;
  char* gB1 = gB0 + (size_t)64 * K * 2;

  unsigned short* lA0 = lA + wave * 512;
  unsigned short* lA1 = lA + 2048 + wave * 512;
  unsigned short* lB0 = lB + wave * 512;
  unsigned short* lB1 = lB + 2048 + wave * 512;

  f32x4 acc[4][4];
#pragma unroll
  for (int i = 0; i < 4; i++)
#pragma unroll
    for (int j = 0; j < 4; j++) acc[i][j] = (f32x4){0.f, 0.f, 0.f, 0.f};

  const int fr = lane & 15;
  const int fk = (lane >> 4) * 8;   // k offset in shorts within a 32-k row

  for (int k0 = 0; k0 < Keff; k0 += 64) {
    ASYNC16(gA0, lA0);
    ASYNC16(gA1, lA1);
    ASYNC16(gB0, lB0);
    ASYNC16(gB1, lB1);
    ASYNC16(gA0 + 64, lA0 + 4096);
    ASYNC16(gA1 + 64, lA1 + 4096);
    ASYNC16(gB0 + 64, lB0 + 4096);
    ASYNC16(gB1 + 64, lB1 + 4096);
    gA0 += 128; gA1 += 128; gB0 += 128; gB1 += 128;
    __syncthreads();

    s16x8 a0[4], b0[4], a1[4], b1[4];
#pragma unroll
    for (int i = 0; i < 4; i++) {
      a0[i] = *(const s16x8*)(lA + (wm + i * 16 + fr) * 32 + fk);
      a1[i] = *(const s16x8*)(lA + 4096 + (wm + i * 16 + fr) * 32 + fk);
    }
#pragma unroll
    for (int j = 0; j < 4; j++) {
      b0[j] = *(const s16x8*)(lB + (wn + j * 16 + fr) * 32 + fk);
      b1[j] = *(const s16x8*)(lB + 4096 + (wn + j * 16 + fr) * 32 + fk);
    }

#pragma unroll
    for (int i = 0; i < 4; i++)
#pragma unroll
      for (int j = 0; j < 4; j++)
        acc[i][j] = __builtin_amdgcn_mfma_f32_16x16x32_bf16(a0[i], b0[j], acc[i][j], 0, 0, 0);
#pragma unroll
    for (int i = 0; i < 4; i++)
#pragma unroll
      for (int j = 0; j < 4; j++)
        acc[i][j] = __builtin_amdgcn_mfma_f32_16x16x32_bf16(a1[i], b1[j], acc[i][j], 0, 0, 0);
    __syncthreads();
  }

#pragma unroll
  for (int j = 0; j < 4; j++) {
    const int col = n0 + wn + j * 16 + fr;
    const float bv = bias[col];
#pragma unroll
    for (int i = 0; i < 4; i++) {
      const int rbase = m0 + wm + i * 16 + (lane >> 4) * 4;
#pragma unroll
      for (int r = 0; r < 4; r++) {
        float v = acc[i][j][r] + bv;
        if (relu) v = fmaxf(v, 0.0f);
        C[(size_t)(rbase + r) * N + col] = f2bf(v);
      }
    }
  }
}

// ---------------- spline math (per (b,d)) ----------------

__device__ __forceinline__ void rq_spline(const unsigned short* __restrict__ pp,
                                          float zv, float& zn, float& lad) {
  const float TAILC = 25.0f;
  const float MIN_WC = 0.001f;
  const float MIN_DC = 0.001f;
  // exp2-folded scale: (1/sqrt(512)) * log2(e)
  const float SCALE2 = 0.06376007120095582f;
  const float LN2 = 0.6931471805599453f;

  s16x8 vw = *(const s16x8*)(pp);
  s16x8 vh = *(const s16x8*)(pp + 8);
  s16x8 vd = *(const s16x8*)(pp + 16);

  bool inside = (zv >= -TAILC) && (zv <= TAILC);
  float z_in = fminf(fmaxf(zv, -TAILC), TAILC);

  // softmax without max-pass or clamps: |params*scale| << 1 here.
  float ew[8], eh[8], sw = 0.f, sh = 0.f;
#pragma unroll
  for (int i = 0; i < 8; i++) {
    ew[i] = exp2f(bf2f((unsigned short)vw[i]) * SCALE2); sw += ew[i];
  }
#pragma unroll
  for (int i = 0; i < 8; i++) {
    eh[i] = exp2f(bf2f((unsigned short)vh[i]) * SCALE2); sh += eh[i];
  }
  float iw = (1.0f - 8.0f * MIN_WC) / sw;
  float ih = (1.0f - 8.0f * MIN_WC) / sh;

  float cumw[9], cumh[9];
  cumw[0] = -TAILC; cumh[0] = -TAILC;
  float cw = 0.f, ch = 0.f;
#pragma unroll
  for (int i = 0; i < 8; i++) {
    cw += MIN_WC + ew[i] * iw;
    ch += MIN_WC + eh[i] * ih;
    cumw[i + 1] = fmaf(2.0f * TAILC, cw, -TAILC);
    cumh[i + 1] = fmaf(2.0f * TAILC, ch, -TAILC);
  }
  cumw[8] = TAILC; cumh[8] = TAILC;

  int idx = 0;
#pragma unroll
  for (int i = 1; i < 8; i++) idx += (z_in >= cumw[i]) ? 1 : 0;

  float in_cw = 0.f, cw1 = 1.f, in_ch = 0.f, ch1 = 1.f, u0 = 0.f, u1 = 0.f;
#pragma unroll
  for (int i = 0; i < 8; i++) {
    if (i == idx) {
      in_cw = cumw[i]; cw1 = cumw[i + 1];
      in_ch = cumh[i]; ch1 = cumh[i + 1];
      u0 = (i > 0) ? bf2f((unsigned short)vd[i - 1]) : 0.0f;
      u1 = (i < 7) ? bf2f((unsigned short)vd[i]) : 0.0f;
    }
  }
  float dd0 = (idx == 0) ? 1.0f
            : MIN_DC + fmaxf(u0, 0.f) + __logf(1.0f + __expf(-fabsf(u0)));
  float dd1 = (idx == 7) ? 1.0f
            : MIN_DC + fmaxf(u1, 0.f) + __logf(1.0f + __expf(-fabsf(u1)));
  float in_w = cw1 - in_cw;
  float in_h = ch1 - in_ch;

  float delta = in_h / in_w;
  float th  = (z_in - in_cw) / in_w;
  float th1 = th * (1.0f - th);
  float th2 = th * th;
  float num = in_h * (delta * th2 + dd0 * th1);
  float den = delta + (dd0 + dd1 - 2.0f * delta) * th1;
  float outz = in_ch + num / den;
  float omt = 1.0f - th;
  float dnum = delta * delta * (dd1 * th2 + 2.0f * delta * th1 + dd0 * omt * omt);
  float l = LN2 * (__log2f(dnum) - 2.0f * __log2f(den));

  zn  = inside ? outz : zv;
  lad = inside ? l : 0.0f;
}

// ---------------- fused GEMM3 + spline, 128x192 tile, triangular K, BK=64 ---------
// grid MUST be (8, 256). K_eff = 64*(bn+1). Two 32-k chunks per barrier pair.
// LDS: staging 40 KB unioned with pT 51.2 KB. Accumulates lad (and on the last
// step -0.5*z'^2) directly into out[] (pre-initialized to -32*ln(2pi)).

__global__ __launch_bounds__(256, 2) void gemm3_spline(
    const unsigned short* __restrict__ A,     // h2 [B][512] (k degree-permuted)
    const unsigned short* __restrict__ Bw,    // w3c[t] [1536][512] (MPAD rows, perm k)
    const float* __restrict__ bias,           // [1536] (MPAD layout)
    float* __restrict__ curf,                 // [B][64]
    unsigned short* __restrict__ A1,          // [B][320]
    float* __restrict__ out,                  // [B] accumulator (= final output)
    int last)
{
  __shared__ alignas(16) union {
    struct { unsigned short A[2 * 128 * 32]; unsigned short B[2 * 192 * 32]; } g;
    unsigned short p[128 * PSTRIDE];
  } sm;

  const int tid  = threadIdx.x;
  const int lane = tid & 63;
  const int wave = tid >> 6;

  const int lin = blockIdx.y * 8 + blockIdx.x;
  const int xcd = lin & 7;
  const int loc = lin >> 3;
  const int m0 = (xcd * 32 + (loc >> 3)) * 128;
  const int bn = loc & 7;
  const int n0 = bn * 192;
  const int Keff = 64 * (bn + 1);   // dims 8bn..8bn+7 need h_deg <= 8bn+7

  const int wm = (wave >> 1) * 64;
  const int wn = (wave & 1) * 96;
  const int fr = lane & 15;
  const int fk = (lane >> 4) * 8;

  // spline-phase mapping (conflict-light): threads 0-127 -> rows, dims 0-3;
  // threads 128-255 -> same rows, dims 4-7.
  const int srow = tid & 127;
  const int sb = m0 + srow;
  const int dl0 = (tid >> 7) * 4;
  const int d0 = bn * 8 + dl0;
  float4 cz = *(const float4*)(curf + (size_t)sb * ZD + d0);
  float bv[6];
#pragma unroll
  for (int j = 0; j < 6; j++) bv[j] = bias[n0 + wn + j * 16 + fr];

  const int f    = tid * 16;
  const int row0 = f >> 6;
  const int colb = f & 63;
  const int K = HID;

  char* gA0 = (char*)A  + ((size_t)(m0 + row0) * K) * 2 + colb;
  char* gA1 = gA0 + (size_t)64 * K * 2;
  char* gB0 = (char*)Bw + ((size_t)(n0 + row0) * K) * 2 + colb;
  char* gB1 = gB0 + (size_t)64 * K * 2;
  char* gB2 = gB1 + (size_t)64 * K * 2;

  unsigned short* lA0 = sm.g.A + wave * 512;
  unsigned short* lA1 = sm.g.A + 2048 + wave * 512;
  unsigned short* lB0 = sm.g.B + wave * 512;
  unsigned short* lB1 = sm.g.B + 2048 + wave * 512;
  unsigned short* lB2 = sm.g.B + 4096 + wave * 512;

  f32x4 acc[4][6];
#pragma unroll
  for (int i = 0; i < 4; i++)
#pragma unroll
    for (int j = 0; j < 6; j++) acc[i][j] = (f32x4){0.f, 0.f, 0.f, 0.f};

  for (int k0 = 0; k0 < Keff; k0 += 64) {
    ASYNC16(gA0, lA0);
    ASYNC16(gA1, lA1);
    ASYNC16(gB0, lB0);
    ASYNC16(gB1, lB1);
    ASYNC16(gB2, lB2);
    ASYNC16(gA0 + 64, lA0 + 4096);
    ASYNC16(gA1 + 64, lA1 + 4096);
    ASYNC16(gB0 + 64, lB0 + 6144);
    ASYNC16(gB1 + 64, lB1 + 6144);
    ASYNC16(gB2 + 64, lB2 + 6144);
    gA0 += 128; gA1 += 128; gB0 += 128; gB1 += 128; gB2 += 128;
    __syncthreads();

    s16x8 a0[4], a1[4], b0[6], b1[6];
#pragma unroll
    for (int i = 0; i < 4; i++) {
      a0[i] = *(const s16x8*)(sm.g.A + (wm + i * 16 + fr) * 32 + fk);
      a1[i] = *(const s16x8*)(sm.g.A + 4096 + (wm + i * 16 + fr) * 32 + fk);
    }
#pragma unroll
    for (int j = 0; j < 6; j++) {
      b0[j] = *(const s16x8*)(sm.g.B + (wn + j * 16 + fr) * 32 + fk);
      b1[j] = *(const s16x8*)(sm.g.B + 6144 + (wn + j * 16 + fr) * 32 + fk);
    }

#pragma unroll
    for (int i = 0; i < 4; i++)
#pragma unroll
      for (int j = 0; j < 6; j++)
        acc[i][j] = __builtin_amdgcn_mfma_f32_16x16x32_bf16(a0[i], b0[j], acc[i][j], 0, 0, 0);
#pragma unroll
    for (int i = 0; i < 4; i++)
#pragma unroll
      for (int j = 0; j < 6; j++)
        acc[i][j] = __builtin_amdgcn_mfma_f32_16x16x32_bf16(a1[i], b1[j], acc[i][j], 0, 0, 0);
    __syncthreads();
  }

  // accumulator + bias -> pT (bf16, padded stride); loop ended with barrier
#pragma unroll
  for (int j = 0; j < 6; j++) {
    const int col = wn + j * 16 + fr;
#pragma unroll
    for (int i = 0; i < 4; i++) {
      const int rbase = wm + i * 16 + (lane >> 4) * 4;
#pragma unroll
      for (int r = 0; r < 4; r++)
        sm.p[(rbase + r) * PSTRIDE + col] = f2bf(acc[i][j][r] + bv[j]);
    }
  }
  __syncthreads();

  // spline: 2 threads per row, 4 dims each
  const unsigned short* pp = sm.p + srow * PSTRIDE + dl0 * MPAD;
  float zn0, zn1, zn2, zn3, l0, l1, l2, l3;
  rq_spline(pp,            cz.x, zn0, l0);
  rq_spline(pp + MPAD,     cz.y, zn1, l1);
  rq_spline(pp + 2 * MPAD, cz.z, zn2, l2);
  rq_spline(pp + 3 * MPAD, cz.w, zn3, l3);

  *(float4*)(curf + (size_t)sb * ZD + d0) = make_float4(zn0, zn1, zn2, zn3);
  union { unsigned int u[2]; unsigned short s[4]; } pk;
  pk.s[0] = f2bf(zn0); pk.s[1] = f2bf(zn1); pk.s[2] = f2bf(zn2); pk.s[3] = f2bf(zn3);
  *(uint2*)(A1 + (size_t)sb * K1 + d0) = make_uint2(pk.u[0], pk.u[1]);

  float contrib = l0 + l1 + l2 + l3;
  if (last)
    contrib -= 0.5f * (zn0 * zn0 + zn1 * zn1 + zn2 * zn2 + zn3 * zn3);
  atomicAdd(&out[sb], contrib);
}

// ---------------- launch ----------------

extern "C" void kernel_launch(void* const* d_in, const int* in_sizes, int n_in,
                              void* d_out, int out_size, void* d_ws, size_t ws_size,
                              hipStream_t stream)
{
  const float* z  = (const float*)d_in[0];
  const float* x  = (const float*)d_in[1];
  const float* W1 = (const float*)d_in[2];
  const float* b1 = (const float*)d_in[3];
  const float* Wc = (const float*)d_in[4];
  const float* bc = (const float*)d_in[5];
  const float* W2 = (const float*)d_in[6];
  const float* b2 = (const float*)d_in[7];
  const float* W3 = (const float*)d_in[8];
  const float* b3 = (const float*)d_in[9];
  float* out = (float*)d_out;
  char* ws = (char*)d_ws;

  size_t oA1 = 0;
  size_t oH1 = oA1 + (size_t)B_ROWS * K1 * 2;
  size_t oH2 = oH1 + (size_t)B_ROWS * HID * 2;
  size_t oCU = oH2 + (size_t)B_ROWS * HID * 2;
  size_t oW1 = oCU + (size_t)B_ROWS * ZD * 4;
  size_t oW2 = oW1 + (size_t)T_STEPS * HID * K1 * 2;
  size_t oW3 = oW2 + (size_t)T_STEPS * HID * HID * 2;
  size_t oB1 = oW3 + (size_t)T_STEPS * NPAD * HID * 2;
  size_t oB2 = oB1 + (size_t)T_STEPS * HID * 4;
  size_t oB3 = oB2 + (size_t)T_STEPS * HID * 4;

  unsigned short* A1  = (unsigned short*)(ws + oA1);
  unsigned short* h1  = (unsigned short*)(ws + oH1);
  unsigned short* h2  = (unsigned short*)(ws + oH2);
  float* curf = (float*)(ws + oCU);
  unsigned short* w1c = (unsigned short*)(ws + oW1);
  unsigned short* w2c = (unsigned short*)(ws + oW2);
  unsigned short* w3c = (unsigned short*)(ws + oW3);
  float* b1c = (float*)(ws + oB1);
  float* b2p = (float*)(ws + oB2);
  float* b3c = (float*)(ws + oB3);

  const int prepw_total = T_STEPS * (HID * K1 + HID * HID + NPAD * HID + 2 * HID + NPAD);
  prep_weights<<<(prepw_total + 255) / 256, 256, 0, stream>>>(
      W1, Wc, W2, W3, b1, bc, b2, b3, w1c, w2c, w3c, b1c, b2p, b3c);
  const int prepd_total = B_ROWS * (XD + ZD);
  prep_data<<<(prepd_total + 255) / 256, 256, 0, stream>>>(x, z, A1, curf, out);

  for (int t = 0; t < T_STEPS; ++t) {
    gemm_bias<<<dim3(4, B_ROWS / 128), 256, 0, stream>>>(
        A1, w1c + (size_t)t * HID * K1, b1c + (size_t)t * HID, h1,
        B_ROWS, HID, K1, 0, 0);
    gemm_bias<<<dim3(4, B_ROWS / 128), 256, 0, stream>>>(
        h1, w2c + (size_t)t * HID * HID, b2p + (size_t)t * HID, h2,
        B_ROWS, HID, HID, 1, 1);
    gemm3_spline<<<dim3(8, B_ROWS / 128), 256, 0, stream>>>(
        h2, w3c + (size_t)t * NPAD * HID, b3c + (size_t)t * NPAD,
        curf, A1, out, (t == T_STEPS - 1) ? 1 : 0);
  }
}